// Round 1
// baseline (5248.445 us; speedup 1.0000x reference)
//
#include <hip/hip_runtime.h>
#include <math.h>

// Fused Conv2d(64->128,3x3,valid) + bias + min(over oc) + tanh(tanh()).
// Round 1: fp32 VALU baseline (no fp32 MFMA on CDNA4).
//
// Grid: (4 ow-tiles of 64, 127 oh-pairs, 16 batch). Block: 256.
// Thread layout: pix = tid&63 (output column within tile), grp = tid>>6
// (oc group of 32). Each thread computes 2 output rows x 32 oc = 64 fp32
// accumulators, so each wave-uniform float4 weight load feeds 8 FMAs.
// x is staged in LDS in 8-ic chunks: [8 ic][4 rows][66 cols] fp32.

__global__ __launch_bounds__(256, 2)
void conv_min_tanh_fp32(const float* __restrict__ xg,
                        const float* __restrict__ wg,
                        const float* __restrict__ bg,
                        float* __restrict__ out) {
    const int tid = threadIdx.x;
    const int pix = tid & 63;
    const int grp = tid >> 6;        // 0..3 -> oc block of 32
    const int ow0 = blockIdx.x * 64;
    const int oh0 = blockIdx.y * 2;
    const int b   = blockIdx.z;

    __shared__ float lds[2112];      // [8 ic][4 rows][66 cols]

    float acc0[32], acc1[32];
    #pragma unroll
    for (int j = 0; j < 32; ++j) { acc0[j] = 0.f; acc1[j] = 0.f; }

    const int ocbase = grp * 32;

    for (int ic0 = 0; ic0 < 64; ic0 += 8) {
        __syncthreads();
        // ---- stage x chunk: ic0..ic0+7, rows oh0..oh0+3, cols ow0..ow0+65
        for (int idx = tid; idx < 2112; idx += 256) {
            int i   = idx / 264;          // ic within chunk
            int rem = idx - i * 264;
            int row = rem / 66;
            int c   = rem - row * 66;
            int col = ow0 + c;
            float v = 0.f;
            if (col < 256)
                v = xg[(((size_t)b * 64 + (ic0 + i)) * 256 + (oh0 + row)) * 256 + col];
            lds[idx] = v;
        }
        __syncthreads();

        // weights for this group's oc block, this ic chunk, as float4.
        // per-oc stride = 576 floats = 144 float4; chunk offset = ic0*9/4 (exact).
        const float4* wg4 = reinterpret_cast<const float4*>(wg)
                            + (size_t)ocbase * 144 + (ic0 * 9) / 4;

        for (int j4 = 0; j4 < 18; ++j4) {   // 18 float4 = 72 taps = 8 ic * 9
            float xs0[4], xs1[4];
            #pragma unroll
            for (int q = 0; q < 4; ++q) {
                int k  = j4 * 4 + q;        // tap index within chunk
                int i  = k / 9;             // ic within chunk
                int r  = k - i * 9;
                int kh = r / 3;
                int kw = r - kh * 3;
                int base = (i * 4 + kh) * 66 + pix + kw;
                xs0[q] = lds[base];         // output row oh0
                xs1[q] = lds[base + 66];    // output row oh0+1
            }
            #pragma unroll
            for (int j = 0; j < 32; ++j) {
                float4 w4 = wg4[(size_t)j * 144 + j4];
                acc0[j] = fmaf(xs0[0], w4.x, acc0[j]);
                acc0[j] = fmaf(xs0[1], w4.y, acc0[j]);
                acc0[j] = fmaf(xs0[2], w4.z, acc0[j]);
                acc0[j] = fmaf(xs0[3], w4.w, acc0[j]);
                acc1[j] = fmaf(xs1[0], w4.x, acc1[j]);
                acc1[j] = fmaf(xs1[1], w4.y, acc1[j]);
                acc1[j] = fmaf(xs1[2], w4.z, acc1[j]);
                acc1[j] = fmaf(xs1[3], w4.w, acc1[j]);
            }
        }
    }

    // ---- epilogue: bias + min over own 32 oc, then min across the 4 groups
    float m0 = 1e30f, m1 = 1e30f;
    #pragma unroll
    for (int j = 0; j < 32; ++j) {
        float bv = bg[ocbase + j];
        m0 = fminf(m0, acc0[j] + bv);
        m1 = fminf(m1, acc1[j] + bv);
    }
    __syncthreads();                 // lds reuse after last compute reads
    lds[grp * 128 + pix]      = m0;
    lds[grp * 128 + 64 + pix] = m1;
    __syncthreads();
    if (grp < 2) {
        int off = grp * 64;          // grp0 -> row oh0, grp1 -> row oh0+1
        float v = fminf(fminf(lds[off + pix],       lds[128 + off + pix]),
                        fminf(lds[256 + off + pix], lds[384 + off + pix]));
        v = tanhf(tanhf(v));
        int ow = ow0 + pix;
        if (ow < 254) {
            int oh = oh0 + grp;
            out[((size_t)b * 254 + oh) * 254 + ow] = v;
        }
    }
}

extern "C" void kernel_launch(void* const* d_in, const int* in_sizes, int n_in,
                              void* d_out, int out_size, void* d_ws, size_t ws_size,
                              hipStream_t stream) {
    const float* x  = (const float*)d_in[0];   // (16,64,256,256)
    const float* w  = (const float*)d_in[1];   // (128,64,3,3)
    const float* bs = (const float*)d_in[2];   // (128,)
    float* out = (float*)d_out;                // (16,1,254,254)

    dim3 grid(4, 127, 16);   // ow tiles, oh pairs, batch
    conv_min_tanh_fp32<<<grid, 256, 0, stream>>>(x, w, bs, out);
}

// Round 2
// 709.444 us; speedup vs baseline: 7.3980x; 7.3980x over previous
//
#include <hip/hip_runtime.h>
#include <math.h>

// Fused Conv2d(64->128,3x3,valid) + bias + min(oc) + tanh(tanh()) via
// bf16 MFMA implicit GEMM (mfma_f32_32x32x16_bf16).
//
// GEMM: M = pixels, N = 128 oc, K = 576 = 9 taps * 64 ic (tap-major, ic-minor).
// Block: 256 thr = 4 waves; tile 128 px (2 rows x 64 cols) x 128 oc.
// Wave w: r = w&1 (output row), nh = w>>1 (oc half). 2x2 outer product of
// 32x32 tiles per wave -> 4 MFMA per k-step (16 k), 36 k-steps.
//
// LDS: xt [row4][icc4][hi2][col66][j8] bf16 (33792 B) - A-frags are single
//      aligned conflict-free ds_read_b128 (half-wave-contiguous).
//      bt [icc4][hi2][oc128][j8] bf16 (16384 B) - B-frags likewise.
//      Epilogue overlays xt with float sm[128][65] (padded, conflict-free).
// Weights pre-transposed to d_ws in fragment order by wtrans kernel.

typedef __attribute__((ext_vector_type(8))) short bf16x8;
typedef __attribute__((ext_vector_type(16))) float f32x16;

static __device__ __forceinline__ short f2bf(float f) {
    // round-to-nearest-even fp32 -> bf16 (inputs are finite normals)
    unsigned u = __float_as_uint(f);
    u += 0x7fffu + ((u >> 16) & 1u);
    return (short)(u >> 16);
}

// d_ws layout: bf16 bits, idx = ((kstep*2 + hi)*128 + oc)*8 + j
// kstep = tap*4 + icc, tap = kh*3 + kw, ic = icc*16 + hi*8 + j. 73728 elems.
__global__ void wtrans(const float* __restrict__ wg, short* __restrict__ wsB) {
    int o = blockIdx.x * 256 + threadIdx.x;   // 0..73727
    int j     = o & 7;
    int oc    = (o >> 3) & 127;
    int hi    = (o >> 10) & 1;
    int kstep = o >> 11;                       // 0..35
    int tap = kstep >> 2, icc = kstep & 3;
    int ic = icc * 16 + hi * 8 + j;
    int kh = tap / 3, kw = tap % 3;
    wsB[o] = f2bf(wg[((oc * 64 + ic) * 3 + kh) * 3 + kw]);
}

__global__ __launch_bounds__(256, 3)
void conv_min_tanh_mfma(const float* __restrict__ xg,
                        const short* __restrict__ wsB,
                        const float* __restrict__ bg,
                        float* __restrict__ out) {
    __shared__ __align__(16) short xt[16896];  // 33792 B
    __shared__ __align__(16) short bt[8192];   // 16384 B

    const int tid  = threadIdx.x;
    const int lane = tid & 63, l31 = lane & 31, hi = lane >> 5;
    const int w    = tid >> 6;
    const int r    = w & 1;        // output row within pair
    const int nh   = w >> 1;       // oc half (0: oc 0-63, 1: oc 64-127)
    const int ow0  = blockIdx.x * 64;
    const int oh0  = blockIdx.y * 2;
    const int b    = blockIdx.z;

    // ---- stage x tile: rows oh0..+3, cols ow0..+65, all 64 ic, as bf16
    {
        const int ic = tid & 63, row = tid >> 6;  // one (ic,row) per thread
        const float* xrow = xg + (((size_t)(b * 64 + ic) * 256) + (oh0 + row)) * 256 + ow0;
        const float4* xrow4 = (const float4*)xrow;
        short* dst = xt + (((row * 4 + (ic >> 4)) * 2 + ((ic >> 3) & 1)) * 66) * 8 + (ic & 7);
        #pragma unroll
        for (int q = 0; q < 16; ++q) {
            float4 v = xrow4[q];
            dst[(q * 4 + 0) * 8] = f2bf(v.x);
            dst[(q * 4 + 1) * 8] = f2bf(v.y);
            dst[(q * 4 + 2) * 8] = f2bf(v.z);
            dst[(q * 4 + 3) * 8] = f2bf(v.w);
        }
        float t0 = 0.f, t1 = 0.f;
        if (ow0 < 192) { t0 = xrow[64]; t1 = xrow[65]; }  // halo cols (OOB -> 0)
        dst[64 * 8] = f2bf(t0);
        dst[65 * 8] = f2bf(t1);
    }

    f32x16 acc00 = {};  // m-tile 0 (cols 0-31)  x n-tile 0 (oc nh*64+0..31)
    f32x16 acc01 = {};  // m-tile 0 x n-tile 1 (oc nh*64+32..63)
    f32x16 acc10 = {};  // m-tile 1 (cols 32-63) x n-tile 0
    f32x16 acc11 = {};  // m-tile 1 x n-tile 1

    const int ocb = nh * 64 + l31;

    #pragma unroll
    for (int tap = 0; tap < 9; ++tap) {
        const int kh = tap / 3, kw = tap % 3;
        // prefetch this tap's B chunk (16 KB) to regs, then LDS broadcast
        uint4 breg[4];
        const uint4* bsrc = (const uint4*)(wsB + tap * 8192);
        #pragma unroll
        for (int q = 0; q < 4; ++q) breg[q] = bsrc[q * 256 + tid];
        __syncthreads();   // prior tap's bt reads (and tap0: xt writes) done
        {
            uint4* bdst = (uint4*)bt;
            #pragma unroll
            for (int q = 0; q < 4; ++q) bdst[q * 256 + tid] = breg[q];
        }
        __syncthreads();   // bt ready

        #pragma unroll
        for (int icc = 0; icc < 4; ++icc) {
            const bf16x8* ap = (const bf16x8*)(xt +
                (((((r + kh) * 4 + icc) * 2 + hi) * 66) + (l31 + kw)) * 8);
            bf16x8 a0 = ap[0];    // cols 0-31 (per-lane col = l31 + kw)
            bf16x8 a1 = ap[32];   // cols 32-63
            const bf16x8* bp = (const bf16x8*)(bt + ((icc * 2 + hi) * 128 + ocb) * 8);
            bf16x8 b0 = bp[0];    // oc n-tile 0
            bf16x8 b1 = bp[32];   // oc n-tile 1
            acc00 = __builtin_amdgcn_mfma_f32_32x32x16_bf16(a0, b0, acc00, 0, 0, 0);
            acc01 = __builtin_amdgcn_mfma_f32_32x32x16_bf16(a0, b1, acc01, 0, 0, 0);
            acc10 = __builtin_amdgcn_mfma_f32_32x32x16_bf16(a1, b0, acc10, 0, 0, 0);
            acc11 = __builtin_amdgcn_mfma_f32_32x32x16_bf16(a1, b1, acc11, 0, 0, 0);
        }
    }

    // ---- epilogue: bias + min over oc, cross-wave via LDS, tanh(tanh), store
    __syncthreads();                  // all xt reads done; overlay as sm
    float* sm = (float*)xt;           // [128 px][65] (pad -> conflict-free)
    const float b0 = bg[nh * 64 + l31];
    const float b1 = bg[nh * 64 + 32 + l31];
    // D layout (32x32): n = lane&31, m = (reg&3) + 8*(reg>>2) + 4*hi  [m74/m101]
    #pragma unroll
    for (int reg = 0; reg < 16; ++reg) {
        int m = (reg & 3) + 8 * (reg >> 2) + 4 * hi;
        float v0 = fminf(acc00[reg] + b0, acc01[reg] + b1);
        float v1 = fminf(acc10[reg] + b0, acc11[reg] + b1);
        sm[(r * 64 + m) * 65 + nh * 32 + l31]      = v0;  // pixel col m
        sm[(r * 64 + 32 + m) * 65 + nh * 32 + l31] = v1;  // pixel col 32+m
    }
    __syncthreads();
    if (tid < 128) {
        const float* rowp = sm + tid * 65;
        float v = 1e30f;
        #pragma unroll
        for (int j = 0; j < 64; ++j) v = fminf(v, rowp[j]);
        v = tanhf(tanhf(v));
        int ow = ow0 + (tid & 63);
        if (ow < 254) {
            int oh = oh0 + (tid >> 6);
            out[((size_t)b * 254 + oh) * 254 + ow] = v;
        }
    }
}

extern "C" void kernel_launch(void* const* d_in, const int* in_sizes, int n_in,
                              void* d_out, int out_size, void* d_ws, size_t ws_size,
                              hipStream_t stream) {
    const float* x  = (const float*)d_in[0];   // (16,64,256,256)
    const float* wg = (const float*)d_in[1];   // (128,64,3,3)
    const float* bs = (const float*)d_in[2];   // (128,)
    float* out = (float*)d_out;                // (16,1,254,254)
    short* wsB = (short*)d_ws;                 // needs 147456 B

    wtrans<<<288, 256, 0, stream>>>(wg, wsB);
    dim3 grid(4, 127, 16);
    conv_min_tanh_mfma<<<grid, 256, 0, stream>>>(x, wsB, bs, out);
}

// Round 3
// 509.039 us; speedup vs baseline: 10.3105x; 1.3937x over previous
//
#include <hip/hip_runtime.h>
#include <math.h>

// Fused Conv2d(64->128,3x3,valid) + bias + min(oc) + tanh(tanh()) via
// bf16 MFMA implicit GEMM (mfma_f32_32x32x16_bf16).
//
// Round 3: barrier-free K-loop.
// Block: 256 thr = 4 waves; tile 4 rows x 64 cols x 128 oc. Wave w handles
// output row oh0+w: 2 m-tiles (cols 0-31/32-63) x 4 n-tiles (oc 32-groups)
// = 8 f32x16 accumulators, 288 MFMAs, NO barriers inside the K-loop.
// x staged once to LDS: xt[row6][icc4][hi2][col66][j8] bf16 (50688 B).
// B fragments read straight from pre-transposed d_ws (147 KB, L2-resident).
// Epilogue: per-lane min over 4 oc + __shfl_xor butterfly over 32 lanes.

typedef __attribute__((ext_vector_type(8))) short bf16x8;
typedef __attribute__((ext_vector_type(16))) float f32x16;

static __device__ __forceinline__ short f2bf(float f) {
    unsigned u = __float_as_uint(f);
    u += 0x7fffu + ((u >> 16) & 1u);
    return (short)(u >> 16);
}

// d_ws layout: bf16 bits, idx = ((kstep*2 + hi)*128 + oc)*8 + j
// kstep = tap*4 + icc, tap = kh*3 + kw, ic = icc*16 + hi*8 + j. 73728 elems.
__global__ void wtrans(const float* __restrict__ wg, short* __restrict__ wsB) {
    int o = blockIdx.x * 256 + threadIdx.x;   // 0..73727
    int j     = o & 7;
    int oc    = (o >> 3) & 127;
    int hi    = (o >> 10) & 1;
    int kstep = o >> 11;                       // 0..35
    int tap = kstep >> 2, icc = kstep & 3;
    int ic = icc * 16 + hi * 8 + j;
    int kh = tap / 3, kw = tap % 3;
    wsB[o] = f2bf(wg[((oc * 64 + ic) * 3 + kh) * 3 + kw]);
}

__global__ __launch_bounds__(256, 2)
void conv_min_tanh_mfma(const float* __restrict__ xg,
                        const short* __restrict__ wsB,
                        const float* __restrict__ bg,
                        float* __restrict__ out) {
    __shared__ __align__(16) short xt[25344];  // [6][4][2][66][8] = 50688 B

    const int tid  = threadIdx.x;
    const int lane = tid & 63, l31 = lane & 31, hi = lane >> 5;
    const int w    = tid >> 6;                 // wave = output row within tile
    const int ow0  = blockIdx.x * 64;
    const int oh0  = blockIdx.y * 4;
    const int b    = blockIdx.z;

    // ---- stage x tile once: rows oh0..oh0+5 (clamped), cols ow0..+65, 64 ic
    for (int idx = tid; idx < 384; idx += 256) {
        const int row = idx >> 6;              // 0..5
        const int ic  = idx & 63;
        const int ih  = min(oh0 + row, 255);
        const float* xrow = xg + (((size_t)(b * 64 + ic) * 256) + ih) * 256 + ow0;
        const float4* xrow4 = (const float4*)xrow;
        short* dst = xt + ((row * 4 + (ic >> 4)) * 2 + ((ic >> 3) & 1)) * 528 + (ic & 7);
        #pragma unroll
        for (int q = 0; q < 16; ++q) {
            float4 v = xrow4[q];
            dst[(q * 4 + 0) * 8] = f2bf(v.x);
            dst[(q * 4 + 1) * 8] = f2bf(v.y);
            dst[(q * 4 + 2) * 8] = f2bf(v.z);
            dst[(q * 4 + 3) * 8] = f2bf(v.w);
        }
        float t0 = 0.f, t1 = 0.f;
        if (ow0 < 192) { t0 = xrow[64]; t1 = xrow[65]; }   // halo (OOB -> 0)
        dst[64 * 8] = f2bf(t0);
        dst[65 * 8] = f2bf(t1);
    }
    __syncthreads();   // the ONLY barrier

    f32x16 acc[2][4];
    #pragma unroll
    for (int m = 0; m < 2; ++m)
        #pragma unroll
        for (int n = 0; n < 4; ++n) acc[m][n] = (f32x16){};

    // ---- K-loop: 36 ksteps x 8 MFMA, A from LDS, B from L2, no barriers
    #pragma unroll
    for (int kstep = 0; kstep < 36; ++kstep) {
        const int tap = kstep >> 2, icc = kstep & 3;
        const int kh = tap / 3, kw = tap % 3;

        const bf16x8* ap = (const bf16x8*)(xt +
            (((w + kh) * 4 + icc) * 2 + hi) * 528 + (l31 + kw) * 8);
        bf16x8 a0 = ap[0];    // cols l31
        bf16x8 a1 = ap[32];   // cols 32+l31

        const bf16x8* bp = (const bf16x8*)(wsB + (((kstep * 2 + hi) * 128) + l31) * 8);
        bf16x8 b0 = bp[0];    // oc l31
        bf16x8 b1 = bp[32];   // oc 32+l31
        bf16x8 b2 = bp[64];   // oc 64+l31
        bf16x8 b3 = bp[96];   // oc 96+l31

        acc[0][0] = __builtin_amdgcn_mfma_f32_32x32x16_bf16(a0, b0, acc[0][0], 0, 0, 0);
        acc[0][1] = __builtin_amdgcn_mfma_f32_32x32x16_bf16(a0, b1, acc[0][1], 0, 0, 0);
        acc[0][2] = __builtin_amdgcn_mfma_f32_32x32x16_bf16(a0, b2, acc[0][2], 0, 0, 0);
        acc[0][3] = __builtin_amdgcn_mfma_f32_32x32x16_bf16(a0, b3, acc[0][3], 0, 0, 0);
        acc[1][0] = __builtin_amdgcn_mfma_f32_32x32x16_bf16(a1, b0, acc[1][0], 0, 0, 0);
        acc[1][1] = __builtin_amdgcn_mfma_f32_32x32x16_bf16(a1, b1, acc[1][1], 0, 0, 0);
        acc[1][2] = __builtin_amdgcn_mfma_f32_32x32x16_bf16(a1, b2, acc[1][2], 0, 0, 0);
        acc[1][3] = __builtin_amdgcn_mfma_f32_32x32x16_bf16(a1, b3, acc[1][3], 0, 0, 0);
    }

    // ---- epilogue: bias + min over oc (4 per lane, then 32-lane butterfly)
    const float bv0 = bg[l31];
    const float bv1 = bg[32 + l31];
    const float bv2 = bg[64 + l31];
    const float bv3 = bg[96 + l31];
    const int oh = oh0 + w;
    #pragma unroll
    for (int reg = 0; reg < 16; ++reg) {
        // D layout (32x32): n = lane&31, m = (reg&3) + 8*(reg>>2) + 4*hi
        const int m = (reg & 3) + 8 * (reg >> 2) + 4 * hi;
        float p0 = fminf(fminf(acc[0][0][reg] + bv0, acc[0][1][reg] + bv1),
                         fminf(acc[0][2][reg] + bv2, acc[0][3][reg] + bv3));
        float p1 = fminf(fminf(acc[1][0][reg] + bv0, acc[1][1][reg] + bv1),
                         fminf(acc[1][2][reg] + bv2, acc[1][3][reg] + bv3));
        #pragma unroll
        for (int mask = 1; mask <= 16; mask <<= 1) {
            p0 = fminf(p0, __shfl_xor(p0, mask, 64));
            p1 = fminf(p1, __shfl_xor(p1, mask, 64));
        }
        if (l31 == 0 && oh < 254) {
            const int owa = ow0 + m, owb = ow0 + 32 + m;
            if (owa < 254)
                out[((size_t)b * 254 + oh) * 254 + owa] = tanhf(tanhf(p0));
            if (owb < 254)
                out[((size_t)b * 254 + oh) * 254 + owb] = tanhf(tanhf(p1));
        }
    }
}

extern "C" void kernel_launch(void* const* d_in, const int* in_sizes, int n_in,
                              void* d_out, int out_size, void* d_ws, size_t ws_size,
                              hipStream_t stream) {
    const float* x  = (const float*)d_in[0];   // (16,64,256,256)
    const float* wg = (const float*)d_in[1];   // (128,64,3,3)
    const float* bs = (const float*)d_in[2];   // (128,)
    float* out = (float*)d_out;                // (16,1,254,254)
    short* wsB = (short*)d_ws;                 // needs 147456 B

    wtrans<<<288, 256, 0, stream>>>(wg, wsB);
    dim3 grid(4, 64, 16);   // ow tiles, oh quads, batch
    conv_min_tanh_mfma<<<grid, 256, 0, stream>>>(x, wsB, bs, out);
}

// Round 4
// 487.777 us; speedup vs baseline: 10.7599x; 1.0436x over previous
//
#include <hip/hip_runtime.h>
#include <math.h>

// Fused Conv2d(64->128,3x3,valid) + bias + min(oc) + tanh(tanh()) via
// bf16 MFMA implicit GEMM (mfma_f32_32x32x16_bf16).
//
// Round 4: occupancy + pipelining.
// Block: 256 thr = 4 waves; tile 2 rows x 64 cols x 128 oc.
// Wave (r = w&1, nh = w>>1): 2 m-tiles (cols 0-31/32-63) x 2 n-tiles
// (oc nh*64+{0,32}) = 4 f32x16 accs, 144 MFMAs, barrier-free K-loop with
// explicit register double-buffer on B (L2-resident pre-transposed d_ws).
// LDS: xt[(row4*4+icc)*2+hi][col66][j8] bf16 = 33792 B -> 4 blocks/CU (50% occ).
// Staging: coalesced global loads, one ds_write_b128 per 8-ic vector.
// Epilogue: LDS transpose (sm[128][65] overlay) + row-min + shfl_xor.

typedef __attribute__((ext_vector_type(8))) short bf16x8;
typedef __attribute__((ext_vector_type(16))) float f32x16;

static __device__ __forceinline__ short f2bf(float f) {
    unsigned u = __float_as_uint(f);
    u += 0x7fffu + ((u >> 16) & 1u);
    return (short)(u >> 16);
}

// d_ws layout: bf16 bits, idx = ((kstep*2 + hi)*128 + oc)*8 + j
// kstep = tap*4 + icc, tap = kh*3 + kw, ic = icc*16 + hi*8 + j. 73728 elems.
__global__ void wtrans(const float* __restrict__ wg, short* __restrict__ wsB) {
    int o4 = blockIdx.x * 256 + threadIdx.x;   // 0..18431 (x4 elements)
    if (o4 >= 18432) return;
    float4 v = ((const float4*)wg)[o4];        // coalesced read
    float f[4] = {v.x, v.y, v.z, v.w};
    int base = o4 * 4;
    #pragma unroll
    for (int q = 0; q < 4; ++q) {
        int e  = base + q;                     // ((oc*64+ic)*3+kh)*3+kw
        int kw = e % 3, r1 = e / 3;
        int kh = r1 % 3, r2 = r1 / 3;
        int ic = r2 & 63, oc = r2 >> 6;
        int tap = kh * 3 + kw;
        int icc = ic >> 4, hi = (ic >> 3) & 1, j = ic & 7;
        int kstep = tap * 4 + icc;
        wsB[((kstep * 2 + hi) * 128 + oc) * 8 + j] = f2bf(f[q]);
    }
}

__global__ __launch_bounds__(256, 4)
void conv_min_tanh_mfma(const float* __restrict__ xg,
                        const short* __restrict__ wsB,
                        const float* __restrict__ bg,
                        float* __restrict__ out) {
    __shared__ __align__(16) short xt[16896];  // [32 g][66 col][8 j] = 33792 B

    const int tid  = threadIdx.x;
    const int lane = tid & 63, l31 = lane & 31, hi = lane >> 5;
    const int w    = tid >> 6;
    const int r    = w & 1;        // output row within pair
    const int nh   = w >> 1;       // oc half
    const int ow0  = blockIdx.x * 64;
    const int oh0  = blockIdx.y * 2;
    const int b    = blockIdx.z;

    // ---- stage x: rows oh0..+3, cols ow0..+65, 64 ic -> 2112 bf16x8 vectors
    #pragma unroll
    for (int t = 0; t < 9; ++t) {
        int idx = t * 256 + tid;
        if (idx < 2112) {
            int g   = idx / 66;               // (row*4+icc)*2+hi
            int col = idx - g * 66;
            int row = g >> 3;
            int icb = ((g >> 1) & 3) * 16 + (g & 1) * 8;
            int iw  = ow0 + col;
            const float* src = xg + (((size_t)(b * 64 + icb) * 256) + (oh0 + row)) * 256 + iw;
            bool valid = iw < 256;
            float f[8];
            #pragma unroll
            for (int j = 0; j < 8; ++j) f[j] = valid ? src[j * 65536] : 0.f;
            bf16x8 v;
            #pragma unroll
            for (int j = 0; j < 8; ++j) v[j] = f2bf(f[j]);
            *(bf16x8*)(xt + g * 528 + col * 8) = v;
        }
    }
    __syncthreads();   // the only K-side barrier

    f32x16 acc00 = {}, acc01 = {}, acc10 = {}, acc11 = {};

    // B fragment pointer for this wave: stride 256 bf16x8 per kstep
    const bf16x8* bp = (const bf16x8*)(wsB + ((size_t)hi * 128 + nh * 64 + l31) * 8);
    bf16x8 bc0 = bp[0], bc1 = bp[32];
    bf16x8 bn0 = bc0, bn1 = bc1;

    #pragma unroll
    for (int k = 0; k < 36; ++k) {
        if (k < 35) {                       // prefetch next kstep's B
            bn0 = bp[(k + 1) * 256];
            bn1 = bp[(k + 1) * 256 + 32];
        }
        const int tap = k >> 2, icc = k & 3;
        const int kh = tap / 3, kw = tap - kh * 3;
        const bf16x8* ap = (const bf16x8*)(xt +
            (((r + kh) * 4 + icc) * 2 + hi) * 528 + (l31 + kw) * 8);
        bf16x8 a0 = ap[0];    // cols l31
        bf16x8 a1 = ap[32];   // cols 32+l31
        acc00 = __builtin_amdgcn_mfma_f32_32x32x16_bf16(a0, bc0, acc00, 0, 0, 0);
        acc01 = __builtin_amdgcn_mfma_f32_32x32x16_bf16(a0, bc1, acc01, 0, 0, 0);
        acc10 = __builtin_amdgcn_mfma_f32_32x32x16_bf16(a1, bc0, acc10, 0, 0, 0);
        acc11 = __builtin_amdgcn_mfma_f32_32x32x16_bf16(a1, bc1, acc11, 0, 0, 0);
        bc0 = bn0; bc1 = bn1;
    }

    // ---- epilogue: bias + partial min (2 oc/lane) -> LDS transpose -> min
    __syncthreads();                  // all xt reads done; overlay as sm
    float* sm = (float*)xt;           // [128 px][65] floats = 33280 B
    const float bv0 = bg[nh * 64 + l31];
    const float bv1 = bg[nh * 64 + 32 + l31];
    #pragma unroll
    for (int reg = 0; reg < 16; ++reg) {
        // D layout (32x32): n = lane&31, m = (reg&3) + 8*(reg>>2) + 4*hi
        const int m = (reg & 3) + 8 * (reg >> 2) + 4 * hi;
        float p0 = fminf(acc00[reg] + bv0, acc01[reg] + bv1);
        float p1 = fminf(acc10[reg] + bv0, acc11[reg] + bv1);
        sm[(r * 64 + m) * 65 + nh * 32 + l31]      = p0;
        sm[(r * 64 + 32 + m) * 65 + nh * 32 + l31] = p1;
    }
    __syncthreads();
    {
        const int px = tid >> 1, half = tid & 1;   // px 0..127
        const float* rowp = sm + px * 65 + half * 32;
        float v = rowp[0];
        #pragma unroll
        for (int j = 1; j < 32; ++j) v = fminf(v, rowp[j]);
        v = fminf(v, __shfl_xor(v, 1, 64));
        if (half == 0) {
            v = tanhf(tanhf(v));
            const int ow = ow0 + (px & 63);
            const int oh = oh0 + (px >> 6);
            if (ow < 254)
                out[((size_t)b * 254 + oh) * 254 + ow] = v;
        }
    }
}

extern "C" void kernel_launch(void* const* d_in, const int* in_sizes, int n_in,
                              void* d_out, int out_size, void* d_ws, size_t ws_size,
                              hipStream_t stream) {
    const float* x  = (const float*)d_in[0];   // (16,64,256,256)
    const float* wg = (const float*)d_in[1];   // (128,64,3,3)
    const float* bs = (const float*)d_in[2];   // (128,)
    float* out = (float*)d_out;                // (16,1,254,254)
    short* wsB = (short*)d_ws;                 // needs 147456 B

    wtrans<<<72, 256, 0, stream>>>(wg, wsB);
    dim3 grid(4, 127, 16);   // ow tiles, oh pairs, batch
    conv_min_tanh_mfma<<<grid, 256, 0, stream>>>(x, wsB, bs, out);
}

// Round 5
// 486.172 us; speedup vs baseline: 10.7954x; 1.0033x over previous
//
#include <hip/hip_runtime.h>
#include <math.h>

// Fused Conv2d(64->128,3x3,valid) + bias + min(oc) + tanh(tanh()) via
// bf16 MFMA implicit GEMM (mfma_f32_32x32x16_bf16).
//
// Round 5: explicit deep pipeline in the K-loop.
//  - B (pre-transposed d_ws, L2-resident): 3-stage register pipeline,
//    prefetch distance 2 ksteps (6 loads in flight) -> covers ~200cyc L2 lat.
//  - A (LDS): 1-kstep-ahead explicit ds_read_b128 prefetch.
//  - B stage-0/1 loads issued before the staging barrier.
// Block: 256 thr = 4 waves; tile 2 rows x 64 cols x 128 oc.
// Wave (r = w&1, nh = w>>1): 2 m-tiles x 2 n-tiles = 4 f32x16 accs,
// 144 MFMAs/wave, one K-side barrier total.
// LDS: xt[(row4*4+icc)*2+hi][col66][j8] bf16 = 33792 B.
// Epilogue: LDS transpose (sm[128][65] overlay) + row-min + shfl_xor.

typedef __attribute__((ext_vector_type(8))) short bf16x8;
typedef __attribute__((ext_vector_type(16))) float f32x16;

static __device__ __forceinline__ short f2bf(float f) {
    unsigned u = __float_as_uint(f);
    u += 0x7fffu + ((u >> 16) & 1u);
    return (short)(u >> 16);
}

// d_ws layout: bf16 bits, idx = ((kstep*2 + hi)*128 + oc)*8 + j
// kstep = tap*4 + icc, tap = kh*3 + kw, ic = icc*16 + hi*8 + j. 73728 elems.
__global__ void wtrans(const float* __restrict__ wg, short* __restrict__ wsB) {
    int o4 = blockIdx.x * 256 + threadIdx.x;   // 0..18431 (x4 elements)
    if (o4 >= 18432) return;
    float4 v = ((const float4*)wg)[o4];        // coalesced read
    float f[4] = {v.x, v.y, v.z, v.w};
    int base = o4 * 4;
    #pragma unroll
    for (int q = 0; q < 4; ++q) {
        int e  = base + q;                     // ((oc*64+ic)*3+kh)*3+kw
        int kw = e % 3, r1 = e / 3;
        int kh = r1 % 3, r2 = r1 / 3;
        int ic = r2 & 63, oc = r2 >> 6;
        int tap = kh * 3 + kw;
        int icc = ic >> 4, hi = (ic >> 3) & 1, j = ic & 7;
        int kstep = tap * 4 + icc;
        wsB[((kstep * 2 + hi) * 128 + oc) * 8 + j] = f2bf(f[q]);
    }
}

__global__ __launch_bounds__(256, 3)
void conv_min_tanh_mfma(const float* __restrict__ xg,
                        const short* __restrict__ wsB,
                        const float* __restrict__ bg,
                        float* __restrict__ out) {
    __shared__ __align__(16) short xt[16896];  // [32 g][66 col][8 j] = 33792 B

    const int tid  = threadIdx.x;
    const int lane = tid & 63, l31 = lane & 31, hi = lane >> 5;
    const int w    = tid >> 6;
    const int r    = w & 1;        // output row within pair
    const int nh   = w >> 1;       // oc half
    const int ow0  = blockIdx.x * 64;
    const int oh0  = blockIdx.y * 2;
    const int b    = blockIdx.z;

    // ---- stage x: rows oh0..+3, cols ow0..+65, 64 ic -> 2112 bf16x8 vectors
    #pragma unroll
    for (int t = 0; t < 9; ++t) {
        int idx = t * 256 + tid;
        if (idx < 2112) {
            int g   = idx / 66;               // (row*4+icc)*2+hi
            int col = idx - g * 66;
            int row = g >> 3;
            int icb = ((g >> 1) & 3) * 16 + (g & 1) * 8;
            int iw  = ow0 + col;
            const float* src = xg + (((size_t)(b * 64 + icb) * 256) + (oh0 + row)) * 256 + iw;
            bool valid = iw < 256;
            float f[8];
            #pragma unroll
            for (int j = 0; j < 8; ++j) f[j] = valid ? src[j * 65536] : 0.f;
            bf16x8 v;
            #pragma unroll
            for (int j = 0; j < 8; ++j) v[j] = f2bf(f[j]);
            *(bf16x8*)(xt + g * 528 + col * 8) = v;
        }
    }

    // B fragment base for this wave: kstep k, n-tile t -> bbase[k*256 + t*32]
    const bf16x8* bbase = (const bf16x8*)(wsB + ((size_t)hi * 128 + nh * 64 + l31) * 8);

    // B pipeline stages: c = kstep k (consume), d = k+1, e = k+2 (issue)
    bf16x8 bc0 = bbase[0],   bc1 = bbase[32];         // k=0
    bf16x8 bd0 = bbase[256], bd1 = bbase[256 + 32];   // k=1
    bf16x8 be0 = bd0, be1 = bd1;

    __syncthreads();   // the only K-side barrier

    f32x16 acc00 = {}, acc01 = {}, acc10 = {}, acc11 = {};

    // A fragments for kstep 0 (tap 0 -> kh=kw=0, icc=0)
    const bf16x8* ap0 = (const bf16x8*)(xt + ((r * 4 + 0) * 2 + hi) * 528 + l31 * 8);
    bf16x8 a0 = ap0[0], a1 = ap0[32];

    #pragma unroll
    for (int k = 0; k < 36; ++k) {
        // issue B prefetch for k+2 (2 loads; 6 in flight max)
        if (k < 34) {
            be0 = bbase[(k + 2) * 256];
            be1 = bbase[(k + 2) * 256 + 32];
        }
        // issue A prefetch for k+1 (2 ds_read_b128)
        bf16x8 an0 = a0, an1 = a1;
        if (k < 35) {
            const int kn = k + 1, tapn = kn >> 2, iccn = kn & 3;
            const int khn = tapn / 3, kwn = tapn - khn * 3;
            const bf16x8* apn = (const bf16x8*)(xt +
                (((r + khn) * 4 + iccn) * 2 + hi) * 528 + (l31 + kwn) * 8);
            an0 = apn[0];
            an1 = apn[32];
        }
        acc00 = __builtin_amdgcn_mfma_f32_32x32x16_bf16(a0, bc0, acc00, 0, 0, 0);
        acc01 = __builtin_amdgcn_mfma_f32_32x32x16_bf16(a0, bc1, acc01, 0, 0, 0);
        acc10 = __builtin_amdgcn_mfma_f32_32x32x16_bf16(a1, bc0, acc10, 0, 0, 0);
        acc11 = __builtin_amdgcn_mfma_f32_32x32x16_bf16(a1, bc1, acc11, 0, 0, 0);
        // rotate pipelines
        a0 = an0; a1 = an1;
        bc0 = bd0; bc1 = bd1;
        bd0 = be0; bd1 = be1;
    }

    // ---- epilogue: bias + partial min (2 oc/lane) -> LDS transpose -> min
    __syncthreads();                  // all xt reads done; overlay as sm
    float* sm = (float*)xt;           // [128 px][65] floats = 33280 B
    const float bv0 = bg[nh * 64 + l31];
    const float bv1 = bg[nh * 64 + 32 + l31];
    #pragma unroll
    for (int reg = 0; reg < 16; ++reg) {
        // D layout (32x32): n = lane&31, m = (reg&3) + 8*(reg>>2) + 4*hi
        const int m = (reg & 3) + 8 * (reg >> 2) + 4 * hi;
        float p0 = fminf(acc00[reg] + bv0, acc01[reg] + bv1);
        float p1 = fminf(acc10[reg] + bv0, acc11[reg] + bv1);
        sm[(r * 64 + m) * 65 + nh * 32 + l31]      = p0;
        sm[(r * 64 + 32 + m) * 65 + nh * 32 + l31] = p1;
    }
    __syncthreads();
    {
        const int px = tid >> 1, half = tid & 1;   // px 0..127
        const float* rowp = sm + px * 65 + half * 32;
        float v = rowp[0];
        #pragma unroll
        for (int j = 1; j < 32; ++j) v = fminf(v, rowp[j]);
        v = fminf(v, __shfl_xor(v, 1, 64));
        if (half == 0) {
            v = tanhf(tanhf(v));
            const int ow = ow0 + (px & 63);
            const int oh = oh0 + (px >> 6);
            if (ow < 254)
                out[((size_t)b * 254 + oh) * 254 + ow] = v;
        }
    }
}

extern "C" void kernel_launch(void* const* d_in, const int* in_sizes, int n_in,
                              void* d_out, int out_size, void* d_ws, size_t ws_size,
                              hipStream_t stream) {
    const float* x  = (const float*)d_in[0];   // (16,64,256,256)
    const float* wg = (const float*)d_in[1];   // (128,64,3,3)
    const float* bs = (const float*)d_in[2];   // (128,)
    float* out = (float*)d_out;                // (16,1,254,254)
    short* wsB = (short*)d_ws;                 // needs 147456 B

    wtrans<<<72, 256, 0, stream>>>(wg, wsB);
    dim3 grid(4, 127, 16);   // ow tiles, oh pairs, batch
    conv_min_tanh_mfma<<<grid, 256, 0, stream>>>(x, wsB, bs, out);
}